// Round 9
// baseline (151.973 us; speedup 1.0000x reference)
//
#include <hip/hip_runtime.h>
#include <hip/hip_bf16.h>

#define N_TOKENS 8192
#define IN_FEAT 1024
#define OUT_FEAT 1024
#define NUM_EXPERT 8

#define BM 128
#define BN 128
#define BK 32   // half-slab; each LDS buffer holds TWO halves (64 K per barrier)

typedef __bf16 bf16x8 __attribute__((ext_vector_type(8)));
typedef float f32x4 __attribute__((ext_vector_type(4)));

// fp32 -> bf16 round-to-nearest-even, two packed into one dword.
__device__ __forceinline__ unsigned int rne16(float x) {
    union { float f; unsigned int u; } c;
    c.f = x;
    unsigned int u = c.u;
    u += 0x7fffu + ((u >> 16) & 1u);
    return u >> 16;
}
__device__ __forceinline__ unsigned int pk2(float x, float y) {
    return rne16(x) | (rne16(y) << 16);
}

// 8x fp32 -> bf16 (hardware cvt, RNE) for the fallback gemm.
__device__ __forceinline__ bf16x8 cvt8(float4 lo, float4 hi) {
    bf16x8 r;
    r[0] = (__bf16)lo.x; r[1] = (__bf16)lo.y;
    r[2] = (__bf16)lo.z; r[3] = (__bf16)lo.w;
    r[4] = (__bf16)hi.x; r[5] = (__bf16)hi.y;
    r[6] = (__bf16)hi.z; r[7] = (__bf16)hi.w;
    return r;
}

// async global->LDS, 16 B per lane; LDS dest is wave-uniform base + lane*16,
// global SOURCE address is per-lane (gather-capable).
__device__ __forceinline__ void load_lds16(const void* g, void* l) {
    __builtin_amdgcn_global_load_lds(
        (const __attribute__((address_space(1))) unsigned int*)g,
        (__attribute__((address_space(3))) unsigned int*)l,
        16, 0, 0);
}

// ---- single-block counting sort, SPILL-PROOF (R7 lesson: arrays -> scratch).
// Named scalars + macro-unrolled expert loop; ballot hist -> t0 scan ->
// ballot-ranked scatter; gate read twice (2nd pass L2-hot). No atomics.

#define HIST1(G) do { int g_ = (G); unsigned long long m_;                   \
    m_ = __ballot(g_ == 0); c0 += (int)__popcll(m_);                         \
    m_ = __ballot(g_ == 1); c1 += (int)__popcll(m_);                         \
    m_ = __ballot(g_ == 2); c2 += (int)__popcll(m_);                         \
    m_ = __ballot(g_ == 3); c3 += (int)__popcll(m_);                         \
    m_ = __ballot(g_ == 4); c4 += (int)__popcll(m_);                         \
    m_ = __ballot(g_ == 5); c5 += (int)__popcll(m_);                         \
    m_ = __ballot(g_ == 6); c6 += (int)__popcll(m_);                         \
    m_ = __ballot(g_ == 7); c7 += (int)__popcll(m_); } while (0)

#define SCAT1(G, TOK) do { int g_ = (G); int tok_ = (TOK);                   \
    unsigned long long m_;                                                   \
    m_ = __ballot(g_ == 0);                                                  \
    if (g_ == 0) perm[o0 + (int)__popcll(m_ & lt)] = tok_;                   \
    o0 += (int)__popcll(m_);                                                 \
    m_ = __ballot(g_ == 1);                                                  \
    if (g_ == 1) perm[o1 + (int)__popcll(m_ & lt)] = tok_;                   \
    o1 += (int)__popcll(m_);                                                 \
    m_ = __ballot(g_ == 2);                                                  \
    if (g_ == 2) perm[o2 + (int)__popcll(m_ & lt)] = tok_;                   \
    o2 += (int)__popcll(m_);                                                 \
    m_ = __ballot(g_ == 3);                                                  \
    if (g_ == 3) perm[o3 + (int)__popcll(m_ & lt)] = tok_;                   \
    o3 += (int)__popcll(m_);                                                 \
    m_ = __ballot(g_ == 4);                                                  \
    if (g_ == 4) perm[o4 + (int)__popcll(m_ & lt)] = tok_;                   \
    o4 += (int)__popcll(m_);                                                 \
    m_ = __ballot(g_ == 5);                                                  \
    if (g_ == 5) perm[o5 + (int)__popcll(m_ & lt)] = tok_;                   \
    o5 += (int)__popcll(m_);                                                 \
    m_ = __ballot(g_ == 6);                                                  \
    if (g_ == 6) perm[o6 + (int)__popcll(m_ & lt)] = tok_;                   \
    o6 += (int)__popcll(m_);                                                 \
    m_ = __ballot(g_ == 7);                                                  \
    if (g_ == 7) perm[o7 + (int)__popcll(m_ & lt)] = tok_;                   \
    o7 += (int)__popcll(m_); } while (0)

__device__ __forceinline__ void sort_core(const int* __restrict__ gate,
                                          int* __restrict__ perm,
                                          int* __restrict__ seg,
                                          int* whist, int* wbase) {
    // whist/wbase: shared arrays of 4*NUM_EXPERT ints each.
    const int t = threadIdx.x;
    const int wave = t >> 6, lane = t & 63;
    const unsigned long long lt = (lane == 0) ? 0ull : (~0ull >> (64 - lane));

    int c0 = 0, c1 = 0, c2 = 0, c3 = 0, c4 = 0, c5 = 0, c6 = 0, c7 = 0;
    #pragma unroll
    for (int j = 0; j < 8; ++j) {
        int4 vv = ((const int4*)gate)[j * 256 + t];   // tokens j*1024+4t+q
        HIST1(vv.x); HIST1(vv.y); HIST1(vv.z); HIST1(vv.w);
    }
    if (lane == 0) {
        whist[wave * 8 + 0] = c0; whist[wave * 8 + 1] = c1;
        whist[wave * 8 + 2] = c2; whist[wave * 8 + 3] = c3;
        whist[wave * 8 + 4] = c4; whist[wave * 8 + 5] = c5;
        whist[wave * 8 + 6] = c6; whist[wave * 8 + 7] = c7;
    }
    __syncthreads();

    if (t == 0) {
        int s = 0;
        #pragma unroll
        for (int e = 0; e < NUM_EXPERT; ++e) {
            seg[e] = s;
            int b = s;
            #pragma unroll
            for (int w = 0; w < 4; ++w) { wbase[w * 8 + e] = b; b += whist[w * 8 + e]; }
            s = b;
        }
        seg[NUM_EXPERT] = s;
    }
    __syncthreads();

    int o0 = wbase[wave * 8 + 0], o1 = wbase[wave * 8 + 1];
    int o2 = wbase[wave * 8 + 2], o3 = wbase[wave * 8 + 3];
    int o4 = wbase[wave * 8 + 4], o5 = wbase[wave * 8 + 5];
    int o6 = wbase[wave * 8 + 6], o7 = wbase[wave * 8 + 7];
    #pragma unroll
    for (int j = 0; j < 8; ++j) {
        int4 vv = ((const int4*)gate)[j * 256 + t];   // L2-hot re-read
        const int tb = j * 1024 + t * 4;
        SCAT1(vv.x, tb);
        SCAT1(vv.y, tb + 1);
        SCAT1(vv.z, tb + 2);
        SCAT1(vv.w, tb + 3);
    }
}

__global__ __launch_bounds__(256) void moe_sort(const int* __restrict__ gate,
                                                int* __restrict__ perm,
                                                int* __restrict__ seg) {
    __shared__ int whist[4 * NUM_EXPERT];
    __shared__ int wbase[4 * NUM_EXPERT];
    sort_core(gate, perm, seg, whist, wbase);
}

// ---- fused prep+sort: block 0 sorts (hidden under BW-bound converts);
// blocks 1..4096 convert inp/weight fp32->bf16. A2 is TOKEN order.
__global__ __launch_bounds__(256) void moe_prep_sort(
    const float* __restrict__ inp,
    const float* __restrict__ weight,
    const int* __restrict__ gate,
    int* __restrict__ perm,
    int* __restrict__ seg,
    unsigned int* __restrict__ A2,
    unsigned int* __restrict__ W2) {

    const int bid = blockIdx.x;
    if (bid == 0) {
        __shared__ int whist[4 * NUM_EXPERT];
        __shared__ int wbase[4 * NUM_EXPERT];
        sort_core(gate, perm, seg, whist, wbase);
        return;
    }
    const int cid = bid - 1;
    const int t = threadIdx.x;
    const int wave = t >> 6, lane = t & 63;
    const float* src;
    unsigned int* dst;
    if (cid < 2048) {
        int row = cid * 4 + wave;           // token order
        src = inp + row * IN_FEAT;
        dst = A2 + row * (IN_FEAT / 2);
    } else {
        int row = (cid - 2048) * 4 + wave;
        src = weight + row * IN_FEAT;
        dst = W2 + row * (IN_FEAT / 2);
    }
    #pragma unroll
    for (int j = 0; j < 4; ++j) {
        float4 v = *(const float4*)(src + j * 256 + lane * 4);
        uint2 o;
        o.x = pk2(v.x, v.y);
        o.y = pk2(v.z, v.w);
        *(uint2*)(dst + j * 128 + lane * 2) = o;
    }
}

// ---- bf16 grouped GEMM: DMA pipeline, 128x128, 64-K per barrier window.
// Each LDS buffer holds TWO 32-K half-slabs (R2's proven layout per half);
// one barrier per buffer -> 16 barriers total (vs 32 at BK=32): the m97-class
// barrier-drain stall is amortized over 32 MFMA + 16 ds_read + 8 DMA issues.
// 64 KB LDS caps at 2 blocks/CU — free, since the grid has only 2 active
// blocks/CU anyway (512 working blocks at uniform routing).
// bid = mtile*64 + ntile*8 + e => bid%8 = e pins each expert to one XCD:
// 2 MB W2 + live A-tiles stay L2-resident. A2 token order; rows gathered
// through perm in the per-lane DMA source.
__global__ __launch_bounds__(256, 2) void moe_gemm(
    const unsigned short* __restrict__ A2,   // bf16 [8192][1024], TOKEN order
    const unsigned short* __restrict__ W2,   // bf16 [8][1024][1024]
    const int* __restrict__ perm,
    const int* __restrict__ seg,
    float* __restrict__ out) {

    const int bid = blockIdx.x;
    const int e = bid & 7;
    const int ntile = (bid >> 3) & 7;
    const int mtile = bid >> 6;

    const int base = seg[e];
    const int cnt = seg[e + 1] - base;
    if (mtile * BM >= cnt) return;
    const int tbase = base + mtile * BM;
    int rows = cnt - mtile * BM; if (rows > BM) rows = BM;

    __shared__ __align__(16) unsigned short lA[2][2][BM * BK];   // 2buf x 2half x 8KB
    __shared__ __align__(16) unsigned short lB[2][2][BN * BK];   // = 64 KB total

    const int t = threadIdx.x;

    // staging: chunk c in {t, t+256}: row = c>>2, k-part p = (c&3)^(row&3)
    const int crow = t >> 2;                 // 0..63
    const int p = (t & 3) ^ (crow & 3);
    int ar0 = tbase + crow;       if (ar0 > N_TOKENS - 1) ar0 = N_TOKENS - 1;
    int ar1 = tbase + 64 + crow;  if (ar1 > N_TOKENS - 1) ar1 = N_TOKENS - 1;
    const unsigned short* gA0 = A2 + (size_t)perm[ar0] * IN_FEAT + p * 8;
    const unsigned short* gA1 = A2 + (size_t)perm[ar1] * IN_FEAT + p * 8;
    const unsigned short* gB0 = W2 + (size_t)e * (OUT_FEAT * IN_FEAT)
                                + (ntile * BN + crow) * IN_FEAT + p * 8;
    const unsigned short* gB1 = gB0 + 64 * IN_FEAT;
    const int dofs = t * 8;                  // chunk t
    const int dofs2 = (t + 256) * 8;         // chunk t+256

    // fragment read addresses (swizzle-matched, per 32-K half)
    const int wave = t >> 6;
    const int lane = t & 63;
    const int wm = (wave & 1) << 6;
    const int wn = (wave >> 1) << 6;
    const int l15 = lane & 15;
    const int quad = lane >> 4;
    const int qx = quad ^ (l15 & 3);
    const int fofsA = (wm + l15) * BK + qx * 8;
    const int fofsB = (wn + l15) * BK + qx * 8;

    f32x4 acc[4][4];
    #pragma unroll
    for (int i = 0; i < 4; ++i)
        #pragma unroll
        for (int j = 0; j < 4; ++j)
            acc[i][j] = (f32x4)0.0f;

    // issue one 32-K half-slab s (0..31) into (buf,half)
    #define STAGE(s, buf, half) do {                                         \
        load_lds16(gA0 + (s) * 32, &lA[buf][half][dofs]);                    \
        load_lds16(gA1 + (s) * 32, &lA[buf][half][dofs2]);                   \
        load_lds16(gB0 + (s) * 32, &lB[buf][half][dofs]);                    \
        load_lds16(gB1 + (s) * 32, &lB[buf][half][dofs2]);                   \
    } while (0)

    #define COMPUTE(buf, half) do {                                          \
        bf16x8 af[4], bq[4];                                                 \
        _Pragma("unroll")                                                    \
        for (int i = 0; i < 4; ++i)                                          \
            af[i] = *(const bf16x8*)&lA[buf][half][fofsA + i * 16 * BK];     \
        _Pragma("unroll")                                                    \
        for (int j = 0; j < 4; ++j)                                          \
            bq[j] = *(const bf16x8*)&lB[buf][half][fofsB + j * 16 * BK];     \
        _Pragma("unroll")                                                    \
        for (int i = 0; i < 4; ++i)                                          \
            _Pragma("unroll")                                                \
            for (int j = 0; j < 4; ++j)                                      \
                acc[i][j] = __builtin_amdgcn_mfma_f32_16x16x32_bf16(         \
                    af[i], bq[j], acc[i][j], 0, 0, 0);                       \
    } while (0)

    // prologue: slabs 0,1 -> buf0
    STAGE(0, 0, 0);
    STAGE(1, 0, 1);

    #pragma unroll 1
    for (int i = 0; i < 16; ++i) {
        const int b = i & 1;
        __syncthreads();   // drains DMA for buf[b]; orders prior buf[b] reads
                           // (2 iters ago) before this iter's writes to buf[b^1]
        if (i < 15) {      // issue slabs 2i+2, 2i+3 -> buf[b^1] (overlap compute)
            if (b == 0) { STAGE(2 * i + 2, 1, 0); STAGE(2 * i + 3, 1, 1); }
            else        { STAGE(2 * i + 2, 0, 0); STAGE(2 * i + 3, 0, 1); }
        }
        if (b == 0) { COMPUTE(0, 0); COMPUTE(0, 1); }
        else        { COMPUTE(1, 0); COMPUTE(1, 1); }
    }

    #undef STAGE
    #undef COMPUTE

    // epilogue: C/D layout col=lane&15, row=quad*4+reg
    #pragma unroll
    for (int mi = 0; mi < 4; ++mi) {
        #pragma unroll
        for (int r = 0; r < 4; ++r) {
            int row = wm + mi * 16 + quad * 4 + r;
            if (row < rows) {
                int token = perm[tbase + row];
                float* op = out + token * OUT_FEAT + ntile * BN + wn;
                #pragma unroll
                for (int ni = 0; ni < 4; ++ni)
                    op[ni * 16 + l15] = acc[mi][ni][r];
            }
        }
    }
}

// ---- fallback (fused-convert gemm, R8-verified) if ws can't hold bf16 copies
__global__ __launch_bounds__(256, 2) void moe_gemm_f(
    const float* __restrict__ inp,
    const float* __restrict__ weight,
    const int* __restrict__ perm,
    const int* __restrict__ seg,
    float* __restrict__ out) {

    const int bid = blockIdx.x;
    const int e = bid & 7;
    const int ntile = (bid >> 3) & 7;
    const int mtile = bid >> 6;

    const int base = seg[e];
    const int cnt = seg[e + 1] - base;
    if (mtile * BM >= cnt) return;
    const int tbase = base + mtile * BM;
    int rows = cnt - mtile * BM; if (rows > BM) rows = BM;

    __shared__ __align__(16) unsigned short lA[2][BM * BK];
    __shared__ __align__(16) unsigned short lB[2][BN * BK];

    const int t = threadIdx.x;
    const int crow = t >> 2;
    const int p = (t & 3) ^ (crow & 3);
    int ar0 = tbase + crow;       if (ar0 > N_TOKENS - 1) ar0 = N_TOKENS - 1;
    int ar1 = tbase + 64 + crow;  if (ar1 > N_TOKENS - 1) ar1 = N_TOKENS - 1;
    const float* gA0 = inp + (size_t)perm[ar0] * IN_FEAT + p * 8;
    const float* gA1 = inp + (size_t)perm[ar1] * IN_FEAT + p * 8;
    const float* gB0 = weight + (size_t)e * (OUT_FEAT * IN_FEAT)
                       + (ntile * BN + crow) * IN_FEAT + p * 8;
    const float* gB1 = gB0 + 64 * IN_FEAT;
    const int dofs = t * 8;
    const int dofs2 = (t + 256) * 8;

    const int wave = t >> 6;
    const int lane = t & 63;
    const int wm = (wave & 1) << 6;
    const int wn = (wave >> 1) << 6;
    const int l15 = lane & 15;
    const int quad = lane >> 4;
    const int qx = quad ^ (l15 & 3);
    const int fofsA = (wm + l15) * BK + qx * 8;
    const int fofsB = (wn + l15) * BK + qx * 8;

    f32x4 acc[4][4];
    #pragma unroll
    for (int i = 0; i < 4; ++i)
        #pragma unroll
        for (int j = 0; j < 4; ++j)
            acc[i][j] = (f32x4)0.0f;

    float4 ra0, ra1, ra2, ra3, rb0, rb1, rb2, rb3;

    ra0 = *(const float4*)(gA0);     ra1 = *(const float4*)(gA0 + 4);
    ra2 = *(const float4*)(gA1);     ra3 = *(const float4*)(gA1 + 4);
    rb0 = *(const float4*)(gB0);     rb1 = *(const float4*)(gB0 + 4);
    rb2 = *(const float4*)(gB1);     rb3 = *(const float4*)(gB1 + 4);
    *(bf16x8*)&lA[0][dofs]  = cvt8(ra0, ra1);
    *(bf16x8*)&lA[0][dofs2] = cvt8(ra2, ra3);
    *(bf16x8*)&lB[0][dofs]  = cvt8(rb0, rb1);
    *(bf16x8*)&lB[0][dofs2] = cvt8(rb2, rb3);

    #pragma unroll 1
    for (int s = 0; s < 32; ++s) {
        const int cur = s & 1;
        const int k0 = (s + 1) * BK;

        if (s < 31) {
            ra0 = *(const float4*)(gA0 + k0);     ra1 = *(const float4*)(gA0 + k0 + 4);
            ra2 = *(const float4*)(gA1 + k0);     ra3 = *(const float4*)(gA1 + k0 + 4);
            rb0 = *(const float4*)(gB0 + k0);     rb1 = *(const float4*)(gB0 + k0 + 4);
            rb2 = *(const float4*)(gB1 + k0);     rb3 = *(const float4*)(gB1 + k0 + 4);
        }

        __syncthreads();

        {
            bf16x8 af[4], bq[4];
            #pragma unroll
            for (int i = 0; i < 4; ++i)
                af[i] = *(const bf16x8*)&lA[cur][fofsA + i * 16 * BK];
            #pragma unroll
            for (int j = 0; j < 4; ++j)
                bq[j] = *(const bf16x8*)&lB[cur][fofsB + j * 16 * BK];
            #pragma unroll
            for (int i = 0; i < 4; ++i)
                #pragma unroll
                for (int j = 0; j < 4; ++j)
                    acc[i][j] = __builtin_amdgcn_mfma_f32_16x16x32_bf16(
                        af[i], bq[j], acc[i][j], 0, 0, 0);
        }

        if (s < 31) {
            *(bf16x8*)&lA[cur ^ 1][dofs]  = cvt8(ra0, ra1);
            *(bf16x8*)&lA[cur ^ 1][dofs2] = cvt8(ra2, ra3);
            *(bf16x8*)&lB[cur ^ 1][dofs]  = cvt8(rb0, rb1);
            *(bf16x8*)&lB[cur ^ 1][dofs2] = cvt8(rb2, rb3);
        }
    }

    #pragma unroll
    for (int mi = 0; mi < 4; ++mi) {
        #pragma unroll
        for (int r = 0; r < 4; ++r) {
            int row = wm + mi * 16 + quad * 4 + r;
            if (row < rows) {
                int token = perm[tbase + row];
                float* op = out + token * OUT_FEAT + ntile * BN + wn;
                #pragma unroll
                for (int ni = 0; ni < 4; ++ni)
                    op[ni * 16 + l15] = acc[mi][ni][r];
            }
        }
    }
}

extern "C" void kernel_launch(void* const* d_in, const int* in_sizes, int n_in,
                              void* d_out, int out_size, void* d_ws, size_t ws_size,
                              hipStream_t stream) {
    const float* inp = (const float*)d_in[0];
    const int* gate = (const int*)d_in[1];
    const float* weight = (const float*)d_in[2];
    float* out = (float*)d_out;

    int* perm = (int*)d_ws;           // 8192 ints
    int* seg = perm + N_TOKENS;       // 9 (pad to 16)

    const size_t need = 65536 + 2ull * N_TOKENS * IN_FEAT * 2;  // 33.6 MB
    if (ws_size >= need) {
        unsigned int* A2 = (unsigned int*)((char*)d_ws + 65536);
        unsigned int* W2 = A2 + (N_TOKENS * IN_FEAT / 2);
        // 1 + 2048 (A rows) + 2048 (W rows); block 0 = fused counting sort
        moe_prep_sort<<<4097, 256, 0, stream>>>(inp, weight, gate, perm, seg,
                                                A2, W2);
        // bid = mtile*64 + ntile*8 + e ; 64 mtiles x 8 ntiles x 8 experts
        moe_gemm<<<4096, 256, 0, stream>>>((const unsigned short*)A2,
                                           (const unsigned short*)W2,
                                           perm, seg, out);
    } else {
        moe_sort<<<1, 256, 0, stream>>>(gate, perm, seg);
        moe_gemm_f<<<4096, 256, 0, stream>>>(inp, weight, perm, seg, out);
    }
}

// Round 10
// 142.133 us; speedup vs baseline: 1.0692x; 1.0692x over previous
//
#include <hip/hip_runtime.h>
#include <hip/hip_bf16.h>

#define N_TOKENS 8192
#define IN_FEAT 1024
#define OUT_FEAT 1024
#define NUM_EXPERT 8

#define BM 128
#define BN 128
#define BK 32

typedef __bf16 bf16x8 __attribute__((ext_vector_type(8)));
typedef float f32x4 __attribute__((ext_vector_type(4)));

// fp32 -> bf16 round-to-nearest-even, two packed into one dword.
__device__ __forceinline__ unsigned int rne16(float x) {
    union { float f; unsigned int u; } c;
    c.f = x;
    unsigned int u = c.u;
    u += 0x7fffu + ((u >> 16) & 1u);
    return u >> 16;
}
__device__ __forceinline__ unsigned int pk2(float x, float y) {
    return rne16(x) | (rne16(y) << 16);
}

// 8x fp32 -> bf16 (hardware cvt, RNE) for the fallback gemm.
__device__ __forceinline__ bf16x8 cvt8(float4 lo, float4 hi) {
    bf16x8 r;
    r[0] = (__bf16)lo.x; r[1] = (__bf16)lo.y;
    r[2] = (__bf16)lo.z; r[3] = (__bf16)lo.w;
    r[4] = (__bf16)hi.x; r[5] = (__bf16)hi.y;
    r[6] = (__bf16)hi.z; r[7] = (__bf16)hi.w;
    return r;
}

// async global->LDS, 16 B per lane; LDS dest is wave-uniform base + lane*16,
// global SOURCE address is per-lane (gather-capable).
__device__ __forceinline__ void load_lds16(const void* g, void* l) {
    __builtin_amdgcn_global_load_lds(
        (const __attribute__((address_space(1))) unsigned int*)g,
        (__attribute__((address_space(3))) unsigned int*)l,
        16, 0, 0);
}

// ---- single-block counting sort, SPILL-PROOF (R7 lesson: arrays -> scratch).
#define HIST1(G) do { int g_ = (G); unsigned long long m_;                   \
    m_ = __ballot(g_ == 0); c0 += (int)__popcll(m_);                         \
    m_ = __ballot(g_ == 1); c1 += (int)__popcll(m_);                         \
    m_ = __ballot(g_ == 2); c2 += (int)__popcll(m_);                         \
    m_ = __ballot(g_ == 3); c3 += (int)__popcll(m_);                         \
    m_ = __ballot(g_ == 4); c4 += (int)__popcll(m_);                         \
    m_ = __ballot(g_ == 5); c5 += (int)__popcll(m_);                         \
    m_ = __ballot(g_ == 6); c6 += (int)__popcll(m_);                         \
    m_ = __ballot(g_ == 7); c7 += (int)__popcll(m_); } while (0)

#define SCAT1(G, TOK) do { int g_ = (G); int tok_ = (TOK);                   \
    unsigned long long m_;                                                   \
    m_ = __ballot(g_ == 0);                                                  \
    if (g_ == 0) perm[o0 + (int)__popcll(m_ & lt)] = tok_;                   \
    o0 += (int)__popcll(m_);                                                 \
    m_ = __ballot(g_ == 1);                                                  \
    if (g_ == 1) perm[o1 + (int)__popcll(m_ & lt)] = tok_;                   \
    o1 += (int)__popcll(m_);                                                 \
    m_ = __ballot(g_ == 2);                                                  \
    if (g_ == 2) perm[o2 + (int)__popcll(m_ & lt)] = tok_;                   \
    o2 += (int)__popcll(m_);                                                 \
    m_ = __ballot(g_ == 3);                                                  \
    if (g_ == 3) perm[o3 + (int)__popcll(m_ & lt)] = tok_;                   \
    o3 += (int)__popcll(m_);                                                 \
    m_ = __ballot(g_ == 4);                                                  \
    if (g_ == 4) perm[o4 + (int)__popcll(m_ & lt)] = tok_;                   \
    o4 += (int)__popcll(m_);                                                 \
    m_ = __ballot(g_ == 5);                                                  \
    if (g_ == 5) perm[o5 + (int)__popcll(m_ & lt)] = tok_;                   \
    o5 += (int)__popcll(m_);                                                 \
    m_ = __ballot(g_ == 6);                                                  \
    if (g_ == 6) perm[o6 + (int)__popcll(m_ & lt)] = tok_;                   \
    o6 += (int)__popcll(m_);                                                 \
    m_ = __ballot(g_ == 7);                                                  \
    if (g_ == 7) perm[o7 + (int)__popcll(m_ & lt)] = tok_;                   \
    o7 += (int)__popcll(m_); } while (0)

__device__ __forceinline__ void sort_core(const int* __restrict__ gate,
                                          int* __restrict__ perm,
                                          int* __restrict__ seg,
                                          int* whist, int* wbase) {
    const int t = threadIdx.x;
    const int wave = t >> 6, lane = t & 63;
    const unsigned long long lt = (lane == 0) ? 0ull : (~0ull >> (64 - lane));

    int c0 = 0, c1 = 0, c2 = 0, c3 = 0, c4 = 0, c5 = 0, c6 = 0, c7 = 0;
    #pragma unroll
    for (int j = 0; j < 8; ++j) {
        int4 vv = ((const int4*)gate)[j * 256 + t];   // tokens j*1024+4t+q
        HIST1(vv.x); HIST1(vv.y); HIST1(vv.z); HIST1(vv.w);
    }
    if (lane == 0) {
        whist[wave * 8 + 0] = c0; whist[wave * 8 + 1] = c1;
        whist[wave * 8 + 2] = c2; whist[wave * 8 + 3] = c3;
        whist[wave * 8 + 4] = c4; whist[wave * 8 + 5] = c5;
        whist[wave * 8 + 6] = c6; whist[wave * 8 + 7] = c7;
    }
    __syncthreads();

    if (t == 0) {
        int s = 0;
        #pragma unroll
        for (int e = 0; e < NUM_EXPERT; ++e) {
            seg[e] = s;
            int b = s;
            #pragma unroll
            for (int w = 0; w < 4; ++w) { wbase[w * 8 + e] = b; b += whist[w * 8 + e]; }
            s = b;
        }
        seg[NUM_EXPERT] = s;
    }
    __syncthreads();

    int o0 = wbase[wave * 8 + 0], o1 = wbase[wave * 8 + 1];
    int o2 = wbase[wave * 8 + 2], o3 = wbase[wave * 8 + 3];
    int o4 = wbase[wave * 8 + 4], o5 = wbase[wave * 8 + 5];
    int o6 = wbase[wave * 8 + 6], o7 = wbase[wave * 8 + 7];
    #pragma unroll
    for (int j = 0; j < 8; ++j) {
        int4 vv = ((const int4*)gate)[j * 256 + t];   // L2-hot re-read
        const int tb = j * 1024 + t * 4;
        SCAT1(vv.x, tb);
        SCAT1(vv.y, tb + 1);
        SCAT1(vv.z, tb + 2);
        SCAT1(vv.w, tb + 3);
    }
}

__global__ __launch_bounds__(256) void moe_sort(const int* __restrict__ gate,
                                                int* __restrict__ perm,
                                                int* __restrict__ seg) {
    __shared__ int whist[4 * NUM_EXPERT];
    __shared__ int wbase[4 * NUM_EXPERT];
    sort_core(gate, perm, seg, whist, wbase);
}

// ---- fused prep+sort: block 0 sorts (hidden under BW-bound converts);
// blocks 1..4096 convert inp/weight fp32->bf16. A2 is TOKEN order.
__global__ __launch_bounds__(256) void moe_prep_sort(
    const float* __restrict__ inp,
    const float* __restrict__ weight,
    const int* __restrict__ gate,
    int* __restrict__ perm,
    int* __restrict__ seg,
    unsigned int* __restrict__ A2,
    unsigned int* __restrict__ W2) {

    const int bid = blockIdx.x;
    if (bid == 0) {
        __shared__ int whist[4 * NUM_EXPERT];
        __shared__ int wbase[4 * NUM_EXPERT];
        sort_core(gate, perm, seg, whist, wbase);
        return;
    }
    const int cid = bid - 1;
    const int t = threadIdx.x;
    const int wave = t >> 6, lane = t & 63;
    const float* src;
    unsigned int* dst;
    if (cid < 2048) {
        int row = cid * 4 + wave;           // token order
        src = inp + row * IN_FEAT;
        dst = A2 + row * (IN_FEAT / 2);
    } else {
        int row = (cid - 2048) * 4 + wave;
        src = weight + row * IN_FEAT;
        dst = W2 + row * (IN_FEAT / 2);
    }
    #pragma unroll
    for (int j = 0; j < 4; ++j) {
        float4 v = *(const float4*)(src + j * 256 + lane * 4);
        uint2 o;
        o.x = pk2(v.x, v.y);
        o.y = pk2(v.z, v.w);
        *(uint2*)(dst + j * 128 + lane * 2) = o;
    }
}

// ---- bf16 grouped GEMM: TRIPLE-buffered counted-vmcnt DMA pipeline (T4).
// Prologue stages slabs 0,1. Each iter: s_waitcnt vmcnt(4) (slab s drained,
// slab s+1's 4 DMAs stay IN FLIGHT across the barrier) -> s_barrier ->
// sched_barrier(0) -> issue slab s+2 into the buffer freed by slab s-1 ->
// compute slab s. Loads never drain to 0 in the main loop (m218 mechanism).
// Swizzle now includes ^((row>>2)&3): fragment ds_read_b128 drops from 4-way
// to 2-way bank aliasing (2-way is free, m136). Source-address and read-side
// changed together (prep/A2 layout untouched).
__global__ __launch_bounds__(256, 3) void moe_gemm(
    const unsigned short* __restrict__ A2,   // bf16 [8192][1024], TOKEN order
    const unsigned short* __restrict__ W2,   // bf16 [8][1024][1024]
    const int* __restrict__ perm,
    const int* __restrict__ seg,
    float* __restrict__ out) {

    const int bid = blockIdx.x;
    const int e = bid & 7;
    const int ntile = (bid >> 3) & 7;
    const int mtile = bid >> 6;

    const int base = seg[e];
    const int cnt = seg[e + 1] - base;
    if (mtile * BM >= cnt) return;
    const int tbase = base + mtile * BM;
    int rows = cnt - mtile * BM; if (rows > BM) rows = BM;

    __shared__ __align__(16) unsigned short lA[3][BM * BK];   // 3 x 8 KB
    __shared__ __align__(16) unsigned short lB[3][BN * BK];   // 3 x 8 KB = 48 KB

    const int t = threadIdx.x;

    // staging: chunk c in {t, t+256}: row = c>>2,
    // k-part p = (c&3) ^ (row&3) ^ ((row>>2)&3)   [bank-conflict fix]
    const int crow = t >> 2;                 // 0..63
    const int p = (t & 3) ^ (crow & 3) ^ ((crow >> 2) & 3);
    int ar0 = tbase + crow;       if (ar0 > N_TOKENS - 1) ar0 = N_TOKENS - 1;
    int ar1 = tbase + 64 + crow;  if (ar1 > N_TOKENS - 1) ar1 = N_TOKENS - 1;
    const unsigned short* gA0 = A2 + (size_t)perm[ar0] * IN_FEAT + p * 8;
    const unsigned short* gA1 = A2 + (size_t)perm[ar1] * IN_FEAT + p * 8;
    const unsigned short* gB0 = W2 + (size_t)e * (OUT_FEAT * IN_FEAT)
                                + (ntile * BN + crow) * IN_FEAT + p * 8;
    const unsigned short* gB1 = gB0 + 64 * IN_FEAT;
    const int dofs = t * 8;                  // chunk t
    const int dofs2 = (t + 256) * 8;         // chunk t+256

    // fragment read addresses (swizzle-matched)
    const int wave = t >> 6;
    const int lane = t & 63;
    const int wm = (wave & 1) << 6;
    const int wn = (wave >> 1) << 6;
    const int l15 = lane & 15;
    const int quad = lane >> 4;
    const int qx = quad ^ (l15 & 3) ^ ((l15 >> 2) & 3);
    const int fofsA = (wm + l15) * BK + qx * 8;
    const int fofsB = (wn + l15) * BK + qx * 8;

    f32x4 acc[4][4];
    #pragma unroll
    for (int i = 0; i < 4; ++i)
        #pragma unroll
        for (int j = 0; j < 4; ++j)
            acc[i][j] = (f32x4)0.0f;

    // issue one 32-K slab s (0..31) into buffer b (4 DMA ops per thread)
    #define STAGE(s, b) do {                                                 \
        load_lds16(gA0 + (s) * 32, &lA[b][dofs]);                            \
        load_lds16(gA1 + (s) * 32, &lA[b][dofs2]);                           \
        load_lds16(gB0 + (s) * 32, &lB[b][dofs]);                            \
        load_lds16(gB1 + (s) * 32, &lB[b][dofs2]);                           \
    } while (0)

    #define COMPUTE(b) do {                                                  \
        bf16x8 af[4], bq[4];                                                 \
        _Pragma("unroll")                                                    \
        for (int i = 0; i < 4; ++i)                                          \
            af[i] = *(const bf16x8*)&lA[b][fofsA + i * 16 * BK];             \
        _Pragma("unroll")                                                    \
        for (int j = 0; j < 4; ++j)                                          \
            bq[j] = *(const bf16x8*)&lB[b][fofsB + j * 16 * BK];             \
        _Pragma("unroll")                                                    \
        for (int i = 0; i < 4; ++i)                                          \
            _Pragma("unroll")                                                \
            for (int j = 0; j < 4; ++j)                                      \
                acc[i][j] = __builtin_amdgcn_mfma_f32_16x16x32_bf16(         \
                    af[i], bq[j], acc[i][j], 0, 0, 0);                       \
    } while (0)

    // prologue: slabs 0,1 -> bufs 0,1 (8 DMAs outstanding per thread)
    STAGE(0, 0);
    STAGE(1, 1);

    int cur = 0;   // buffer holding slab s
    int stg = 2;   // buffer receiving slab s+2
    #pragma unroll 1
    for (int s = 0; s < 30; ++s) {
        // drain slab s only; slab s+1's 4 loads stay in flight across barrier
        asm volatile("s_waitcnt vmcnt(4)" ::: "memory");
        __builtin_amdgcn_s_barrier();
        __builtin_amdgcn_sched_barrier(0);
        STAGE(s + 2, stg);        // buf freed by compute(s-1), barrier-ordered
        COMPUTE(cur);
        cur = (cur == 2) ? 0 : cur + 1;
        stg = (stg == 2) ? 0 : stg + 1;
    }
    // tail: slabs 30 (buf0), 31 (buf1); full drain is fine here
    __syncthreads();
    COMPUTE(0);
    __syncthreads();
    COMPUTE(1);

    #undef STAGE
    #undef COMPUTE

    // epilogue: C/D layout col=lane&15, row=quad*4+reg
    #pragma unroll
    for (int mi = 0; mi < 4; ++mi) {
        #pragma unroll
        for (int r = 0; r < 4; ++r) {
            int row = wm + mi * 16 + quad * 4 + r;
            if (row < rows) {
                int token = perm[tbase + row];
                float* op = out + token * OUT_FEAT + ntile * BN + wn;
                #pragma unroll
                for (int ni = 0; ni < 4; ++ni)
                    op[ni * 16 + l15] = acc[mi][ni][r];
            }
        }
    }
}

// ---- fallback (fused-convert gemm, R8-verified) if ws can't hold bf16 copies
__global__ __launch_bounds__(256, 2) void moe_gemm_f(
    const float* __restrict__ inp,
    const float* __restrict__ weight,
    const int* __restrict__ perm,
    const int* __restrict__ seg,
    float* __restrict__ out) {

    const int bid = blockIdx.x;
    const int e = bid & 7;
    const int ntile = (bid >> 3) & 7;
    const int mtile = bid >> 6;

    const int base = seg[e];
    const int cnt = seg[e + 1] - base;
    if (mtile * BM >= cnt) return;
    const int tbase = base + mtile * BM;
    int rows = cnt - mtile * BM; if (rows > BM) rows = BM;

    __shared__ __align__(16) unsigned short lA[2][BM * BK];
    __shared__ __align__(16) unsigned short lB[2][BN * BK];

    const int t = threadIdx.x;
    const int crow = t >> 2;
    const int p = (t & 3) ^ (crow & 3);
    int ar0 = tbase + crow;       if (ar0 > N_TOKENS - 1) ar0 = N_TOKENS - 1;
    int ar1 = tbase + 64 + crow;  if (ar1 > N_TOKENS - 1) ar1 = N_TOKENS - 1;
    const float* gA0 = inp + (size_t)perm[ar0] * IN_FEAT + p * 8;
    const float* gA1 = inp + (size_t)perm[ar1] * IN_FEAT + p * 8;
    const float* gB0 = weight + (size_t)e * (OUT_FEAT * IN_FEAT)
                       + (ntile * BN + crow) * IN_FEAT + p * 8;
    const float* gB1 = gB0 + 64 * IN_FEAT;
    const int dofs = t * 8;
    const int dofs2 = (t + 256) * 8;

    const int wave = t >> 6;
    const int lane = t & 63;
    const int wm = (wave & 1) << 6;
    const int wn = (wave >> 1) << 6;
    const int l15 = lane & 15;
    const int quad = lane >> 4;
    const int qx = quad ^ (l15 & 3);
    const int fofsA = (wm + l15) * BK + qx * 8;
    const int fofsB = (wn + l15) * BK + qx * 8;

    f32x4 acc[4][4];
    #pragma unroll
    for (int i = 0; i < 4; ++i)
        #pragma unroll
        for (int j = 0; j < 4; ++j)
            acc[i][j] = (f32x4)0.0f;

    float4 ra0, ra1, ra2, ra3, rb0, rb1, rb2, rb3;

    ra0 = *(const float4*)(gA0);     ra1 = *(const float4*)(gA0 + 4);
    ra2 = *(const float4*)(gA1);     ra3 = *(const float4*)(gA1 + 4);
    rb0 = *(const float4*)(gB0);     rb1 = *(const float4*)(gB0 + 4);
    rb2 = *(const float4*)(gB1);     rb3 = *(const float4*)(gB1 + 4);
    *(bf16x8*)&lA[0][dofs]  = cvt8(ra0, ra1);
    *(bf16x8*)&lA[0][dofs2] = cvt8(ra2, ra3);
    *(bf16x8*)&lB[0][dofs]  = cvt8(rb0, rb1);
    *(bf16x8*)&lB[0][dofs2] = cvt8(rb2, rb3);

    #pragma unroll 1
    for (int s = 0; s < 32; ++s) {
        const int cur = s & 1;
        const int k0 = (s + 1) * BK;

        if (s < 31) {
            ra0 = *(const float4*)(gA0 + k0);     ra1 = *(const float4*)(gA0 + k0 + 4);
            ra2 = *(const float4*)(gA1 + k0);     ra3 = *(const float4*)(gA1 + k0 + 4);
            rb0 = *(const float4*)(gB0 + k0);     rb1 = *(const float4*)(gB0 + k0 + 4);
            rb2 = *(const float4*)(gB1 + k0);     rb3 = *(const float4*)(gB1 + k0 + 4);
        }

        __syncthreads();

        {
            bf16x8 af[4], bq[4];
            #pragma unroll
            for (int i = 0; i < 4; ++i)
                af[i] = *(const bf16x8*)&lA[cur][fofsA + i * 16 * BK];
            #pragma unroll
            for (int j = 0; j < 4; ++j)
                bq[j] = *(const bf16x8*)&lB[cur][fofsB + j * 16 * BK];
            #pragma unroll
            for (int i = 0; i < 4; ++i)
                #pragma unroll
                for (int j = 0; j < 4; ++j)
                    acc[i][j] = __builtin_amdgcn_mfma_f32_16x16x32_bf16(
                        af[i], bq[j], acc[i][j], 0, 0, 0);
        }

        if (s < 31) {
            *(bf16x8*)&lA[cur ^ 1][dofs]  = cvt8(ra0, ra1);
            *(bf16x8*)&lA[cur ^ 1][dofs2] = cvt8(ra2, ra3);
            *(bf16x8*)&lB[cur ^ 1][dofs]  = cvt8(rb0, rb1);
            *(bf16x8*)&lB[cur ^ 1][dofs2] = cvt8(rb2, rb3);
        }
    }

    #pragma unroll
    for (int mi = 0; mi < 4; ++mi) {
        #pragma unroll
        for (int r = 0; r < 4; ++r) {
            int row = wm + mi * 16 + quad * 4 + r;
            if (row < rows) {
                int token = perm[tbase + row];
                float* op = out + token * OUT_FEAT + ntile * BN + wn;
                #pragma unroll
                for (int ni = 0; ni < 4; ++ni)
                    op[ni * 16 + l15] = acc[mi][ni][r];
            }
        }
    }
}

extern "C" void kernel_launch(void* const* d_in, const int* in_sizes, int n_in,
                              void* d_out, int out_size, void* d_ws, size_t ws_size,
                              hipStream_t stream) {
    const float* inp = (const float*)d_in[0];
    const int* gate = (const int*)d_in[1];
    const float* weight = (const float*)d_in[2];
    float* out = (float*)d_out;

    int* perm = (int*)d_ws;           // 8192 ints
    int* seg = perm + N_TOKENS;       // 9 (pad to 16)

    const size_t need = 65536 + 2ull * N_TOKENS * IN_FEAT * 2;  // 33.6 MB
    if (ws_size >= need) {
        unsigned int* A2 = (unsigned int*)((char*)d_ws + 65536);
        unsigned int* W2 = A2 + (N_TOKENS * IN_FEAT / 2);
        // 1 + 2048 (A rows) + 2048 (W rows); block 0 = fused counting sort
        moe_prep_sort<<<4097, 256, 0, stream>>>(inp, weight, gate, perm, seg,
                                                A2, W2);
        // bid = mtile*64 + ntile*8 + e ; 64 mtiles x 8 ntiles x 8 experts
        moe_gemm<<<4096, 256, 0, stream>>>((const unsigned short*)A2,
                                           (const unsigned short*)W2,
                                           perm, seg, out);
    } else {
        moe_sort<<<1, 256, 0, stream>>>(gate, perm, seg);
        moe_gemm_f<<<4096, 256, 0, stream>>>(inp, weight, perm, seg, out);
    }
}